// Round 4
// baseline (199.030 us; speedup 1.0000x reference)
//
#include <hip/hip_runtime.h>

#define D_MODEL 128
#define HIDDEN 64
#define WPB 8                 // waves per block
#define NTHREADS (WPB * 64)
#define NBLOCKS 512           // persistent: 2 blocks/CU on 256 CUs
#define W1_STRIDE 132         // 128 + 4 pad: lane stride 4 banks -> <=2-way/phase
#define W2_STRIDE 68          // 64 + 4 pad
#define SEG_BATCH 4           // segments pooled per MLP pass

// Kernel 1: segment start offsets from sorted segment_ids.
__global__ void seg_bounds_kernel(const int* __restrict__ seg, int n, int B,
                                  int* __restrict__ seg_start) {
  int i = blockIdx.x * blockDim.x + threadIdx.x;
  if (i >= n) return;
  int s = seg[i];
  if (i == 0) {
    for (int t = 0; t <= s; ++t) seg_start[t] = 0;
  } else {
    int p = seg[i - 1];
    for (int t = p + 1; t <= s; ++t) seg_start[t] = i;
  }
  if (i == n - 1) {
    for (int t = s + 1; t <= B; ++t) seg_start[t] = n;
  }
}

__device__ __forceinline__ float silu(float x) {
  return x / (1.0f + __expf(-x));
}
__device__ __forceinline__ float4 f4add(float4 a, float4 b) {
  return make_float4(a.x + b.x, a.y + b.y, a.z + b.z, a.w + b.w);
}
__device__ __forceinline__ float wave_sum(float p) {
#pragma unroll
  for (int off = 32; off >= 1; off >>= 1) p += __shfl_xor(p, off);
  return p;
}

// Kernel 2: persistent waves, contiguous segment chunks. Pool SEG_BATCH
// segments (4-deep unrolled streaming), prefetch next batch's first loads,
// then one batched MLP pass (weight LDS reads amortized 4x).
__global__ __launch_bounds__(NTHREADS, 4) void pool_mlp_kernel(
    const float* __restrict__ h, const int* __restrict__ seg_start,
    const float* __restrict__ W1, const float* __restrict__ b1,
    const float* __restrict__ W2, const float* __restrict__ b2,
    const float* __restrict__ W3, const float* __restrict__ b3,
    float* __restrict__ out, int B, int n_atoms) {
  __shared__ float sW1T[HIDDEN * W1_STRIDE];              // 33.0 KB
  __shared__ float sW2T[HIDDEN * W2_STRIDE];              // 17.0 KB
  __shared__ float pooled_lds[WPB][SEG_BATCH][D_MODEL];   // 16 KB
  __shared__ float x1_lds[WPB][SEG_BATCH][HIDDEN];        // 8 KB

  const int tid = threadIdx.x;

  // ---- one-time staging: W1 (k,j) -> sW1T[j][k], W2 likewise (transposed).
#pragma unroll
  for (int i = tid; i < (D_MODEL * HIDDEN) / 4; i += NTHREADS) {
    float4 v = reinterpret_cast<const float4*>(W1)[i];
    int k = i >> 4;                 // 16 float4 per k-row (HIDDEN=64)
    int j = (4 * i) & (HIDDEN - 1);
    sW1T[(j + 0) * W1_STRIDE + k] = v.x;
    sW1T[(j + 1) * W1_STRIDE + k] = v.y;
    sW1T[(j + 2) * W1_STRIDE + k] = v.z;
    sW1T[(j + 3) * W1_STRIDE + k] = v.w;
  }
#pragma unroll
  for (int i = tid; i < (HIDDEN * HIDDEN) / 4; i += NTHREADS) {
    float4 v = reinterpret_cast<const float4*>(W2)[i];
    int k = i >> 4;
    int j = (4 * i) & (HIDDEN - 1);
    sW2T[(j + 0) * W2_STRIDE + k] = v.x;
    sW2T[(j + 1) * W2_STRIDE + k] = v.y;
    sW2T[(j + 2) * W2_STRIDE + k] = v.z;
    sW2T[(j + 3) * W2_STRIDE + k] = v.w;
  }
  __syncthreads();  // only block barrier in the kernel

  const int wave = tid >> 6;
  const int lane = tid & 63;
  const float b1l = b1[lane];
  const float b2l = b2[lane];
  const float w3l = W3[lane];
  const float b3l = b3[0];

  // balanced contiguous chunk per wave
  const int G = gridDim.x * WPB;
  const int g = blockIdx.x * WPB + wave;
  const int base = B / G;
  const int rem = B - base * G;
  const int my_cnt = base + (g < rem ? 1 : 0);
  const int my_s0 = g * base + (g < rem ? g : rem);
  if (my_cnt == 0) return;

  const int half = lane >> 5;   // lanes 0..31 even atoms, 32..63 odd atoms
  const int l32 = lane & 31;
  const float4* __restrict__ hv = reinterpret_cast<const float4*>(h);
  const float4* __restrict__ w1v =
      reinterpret_cast<const float4*>(&sW1T[lane * W1_STRIDE]);
  const float4* __restrict__ w2v =
      reinterpret_cast<const float4*>(&sW2T[lane * W2_STRIDE]);

  float4 pf0, pf1, pf2, pf3;  // prefetch regs (guarded by have_pf)
  bool have_pf = false;

  int start = seg_start[my_s0];
  for (int si = 0; si < my_cnt; si += SEG_BATCH) {
    const int nb = min(SEG_BATCH, my_cnt - si);

    // ---- pool nb segments (one contiguous stream; 1KB per wave load instr)
    for (int b = 0; b < nb; ++b) {
      const int end = seg_start[my_s0 + si + b + 1];
      const int cnt = end - start;
      float4 acc0 = make_float4(0.f, 0.f, 0.f, 0.f);
      float4 acc1 = acc0, acc2 = acc0, acc3 = acc0;
      int a = start + half;
      if (have_pf) {  // prefetched atoms a, a+2, a+4, a+6 (clamped loads)
        if (a < end) acc0 = f4add(acc0, pf0);
        if (a + 2 < end) acc1 = f4add(acc1, pf1);
        if (a + 4 < end) acc2 = f4add(acc2, pf2);
        if (a + 6 < end) acc3 = f4add(acc3, pf3);
        a += 8;
        have_pf = false;
      }
      for (; a + 6 < end; a += 8) {  // 4 loads in flight
        float4 v0 = hv[(a + 0) * 32 + l32];
        float4 v1 = hv[(a + 2) * 32 + l32];
        float4 v2 = hv[(a + 4) * 32 + l32];
        float4 v3 = hv[(a + 6) * 32 + l32];
        acc0 = f4add(acc0, v0);
        acc1 = f4add(acc1, v1);
        acc2 = f4add(acc2, v2);
        acc3 = f4add(acc3, v3);
      }
      if (a < end) {  // tail: up to 3 atoms/half, issued together (1 latency)
        const int c1 = min(a + 2, n_atoms - 1);
        const int c2 = min(a + 4, n_atoms - 1);
        float4 v0 = hv[a * 32 + l32];
        float4 v1 = hv[c1 * 32 + l32];
        float4 v2 = hv[c2 * 32 + l32];
        acc0 = f4add(acc0, v0);
        if (a + 2 < end) acc1 = f4add(acc1, v1);
        if (a + 4 < end) acc2 = f4add(acc2, v2);
      }
      acc0 = f4add(f4add(acc0, acc1), f4add(acc2, acc3));
      acc0.x += __shfl_xor(acc0.x, 32);
      acc0.y += __shfl_xor(acc0.y, 32);
      acc0.z += __shfl_xor(acc0.z, 32);
      acc0.w += __shfl_xor(acc0.w, 32);
      const float inv = 1.0f / (float)max(cnt, 1);
      if (half == 0) {
        reinterpret_cast<float4*>(&pooled_lds[wave][b][0])[l32] = make_float4(
            acc0.x * inv, acc0.y * inv, acc0.z * inv, acc0.w * inv);
      }
      start = end;  // contiguous chunk
    }
    __builtin_amdgcn_wave_barrier();

    // ---- prefetch next batch's first 8 atoms; stays in flight through MLP
    if (si + SEG_BATCH < my_cnt) {
      const int pa = start + half;
      const int c0 = min(pa + 0, n_atoms - 1);
      const int c1 = min(pa + 2, n_atoms - 1);
      const int c2 = min(pa + 4, n_atoms - 1);
      const int c3 = min(pa + 6, n_atoms - 1);
      pf0 = hv[c0 * 32 + l32];
      pf1 = hv[c1 * 32 + l32];
      pf2 = hv[c2 * 32 + l32];
      pf3 = hv[c3 * 32 + l32];
      have_pf = true;
    }

    // ---- batched MLP: lane j = hidden unit j, 4 segments per weight read.
    // (slots b >= nb compute on stale-but-finite LDS; their outputs unwritten)
    const float4* pv0 = reinterpret_cast<const float4*>(&pooled_lds[wave][0][0]);
    const float4* pv1 = reinterpret_cast<const float4*>(&pooled_lds[wave][1][0]);
    const float4* pv2 = reinterpret_cast<const float4*>(&pooled_lds[wave][2][0]);
    const float4* pv3 = reinterpret_cast<const float4*>(&pooled_lds[wave][3][0]);
    float a1b0 = b1l, a1b1 = b1l, a1b2 = b1l, a1b3 = b1l;
#pragma unroll 8
    for (int t = 0; t < D_MODEL / 4; ++t) {
      float4 w = w1v[t];
      float4 p0 = pv0[t], p1 = pv1[t], p2 = pv2[t], p3 = pv3[t];
      a1b0 = fmaf(p0.x, w.x, a1b0); a1b0 = fmaf(p0.y, w.y, a1b0);
      a1b0 = fmaf(p0.z, w.z, a1b0); a1b0 = fmaf(p0.w, w.w, a1b0);
      a1b1 = fmaf(p1.x, w.x, a1b1); a1b1 = fmaf(p1.y, w.y, a1b1);
      a1b1 = fmaf(p1.z, w.z, a1b1); a1b1 = fmaf(p1.w, w.w, a1b1);
      a1b2 = fmaf(p2.x, w.x, a1b2); a1b2 = fmaf(p2.y, w.y, a1b2);
      a1b2 = fmaf(p2.z, w.z, a1b2); a1b2 = fmaf(p2.w, w.w, a1b2);
      a1b3 = fmaf(p3.x, w.x, a1b3); a1b3 = fmaf(p3.y, w.y, a1b3);
      a1b3 = fmaf(p3.z, w.z, a1b3); a1b3 = fmaf(p3.w, w.w, a1b3);
    }
    x1_lds[wave][0][lane] = silu(a1b0);
    x1_lds[wave][1][lane] = silu(a1b1);
    x1_lds[wave][2][lane] = silu(a1b2);
    x1_lds[wave][3][lane] = silu(a1b3);
    __builtin_amdgcn_wave_barrier();

    const float4* x10 = reinterpret_cast<const float4*>(&x1_lds[wave][0][0]);
    const float4* x11 = reinterpret_cast<const float4*>(&x1_lds[wave][1][0]);
    const float4* x12 = reinterpret_cast<const float4*>(&x1_lds[wave][2][0]);
    const float4* x13 = reinterpret_cast<const float4*>(&x1_lds[wave][3][0]);
    float a2b0 = b2l, a2b1 = b2l, a2b2 = b2l, a2b3 = b2l;
#pragma unroll 8
    for (int t = 0; t < HIDDEN / 4; ++t) {
      float4 w = w2v[t];
      float4 p0 = x10[t], p1 = x11[t], p2 = x12[t], p3 = x13[t];
      a2b0 = fmaf(p0.x, w.x, a2b0); a2b0 = fmaf(p0.y, w.y, a2b0);
      a2b0 = fmaf(p0.z, w.z, a2b0); a2b0 = fmaf(p0.w, w.w, a2b0);
      a2b1 = fmaf(p1.x, w.x, a2b1); a2b1 = fmaf(p1.y, w.y, a2b1);
      a2b1 = fmaf(p1.z, w.z, a2b1); a2b1 = fmaf(p1.w, w.w, a2b1);
      a2b2 = fmaf(p2.x, w.x, a2b2); a2b2 = fmaf(p2.y, w.y, a2b2);
      a2b2 = fmaf(p2.z, w.z, a2b2); a2b2 = fmaf(p2.w, w.w, a2b2);
      a2b3 = fmaf(p3.x, w.x, a2b3); a2b3 = fmaf(p3.y, w.y, a2b3);
      a2b3 = fmaf(p3.z, w.z, a2b3); a2b3 = fmaf(p3.w, w.w, a2b3);
    }
    // layer 3: 4 butterfly dot-reductions
    float r0 = wave_sum(silu(a2b0) * w3l);
    float r1 = wave_sum(silu(a2b1) * w3l);
    float r2 = wave_sum(silu(a2b2) * w3l);
    float r3 = wave_sum(silu(a2b3) * w3l);
    float val = (lane == 0) ? r0 : (lane == 1) ? r1 : (lane == 2) ? r2 : r3;
    if (lane < nb) out[my_s0 + si + lane] = val + b3l;
  }
}

extern "C" void kernel_launch(void* const* d_in, const int* in_sizes, int n_in,
                              void* d_out, int out_size, void* d_ws, size_t ws_size,
                              hipStream_t stream) {
  const float* h = (const float*)d_in[0];
  const int* seg = (const int*)d_in[1];
  // d_in[2] = num_segments (device scalar; use out_size instead — host-known)
  const float* W1 = (const float*)d_in[3];
  const float* b1 = (const float*)d_in[4];
  const float* W2 = (const float*)d_in[5];
  const float* b2 = (const float*)d_in[6];
  const float* W3 = (const float*)d_in[7];
  const float* b3 = (const float*)d_in[8];
  float* out = (float*)d_out;

  const int n = in_sizes[1];      // number of atoms
  const int B = out_size;         // number of segments

  int* seg_start = (int*)d_ws;    // B+1 ints

  {
    int threads = 256;
    int blocks = (n + threads - 1) / threads;
    seg_bounds_kernel<<<blocks, threads, 0, stream>>>(seg, n, B, seg_start);
  }
  {
    pool_mlp_kernel<<<NBLOCKS, NTHREADS, 0, stream>>>(
        h, seg_start, W1, b1, W2, b2, W3, b3, out, B, n);
  }
}